// Round 14
// baseline (77.828 us; speedup 1.0000x reference)
//
#include <hip/hip_runtime.h>
#include <hip/hip_bf16.h>

// CT radiological path length: rpl[s][d] = sum_i vols[nearest(src_s + t_i*(dst_d-src_s))] * len/n
// VOL fixed at 256. Round 14: cvt re-threaded as one 16B brick-chunk per thread (lx slow,
// brick z-fastest): coalesced 1KB reads AND 16B-per-lane stores (4x fewer store instrs,
// was 4B scattered). Sort + ray kernel IDENTICAL to R13 best (total 76.4, ray 48.3):
// u8 4x4x4-brick volume, bit-op brick_addr, 13-bit Morton register-cached single-block
// sort, blocked ray order, bijective XCD swizzle, interior fast path, int accumulation.

#define VOLD 256
#define NB 8192       // 13-bit Morton prefix buckets
#define SUBS 8        // threads per ray
#define NCHUNK 8      // dest chunks == XCDs
#define MAXI 32       // register-cached dests per sort thread (covers n_dst <= 32768)

__device__ __forceinline__ int brick_addr(int ix, int iy, int iz) {
    return ((ix & 252) << 16) | ((iy & 252) << 10) | ((iz & 252) << 4)
         | ((ix & 3) << 4)   | ((iy & 3) << 2)    | (iz & 3);
}

__device__ __forceinline__ unsigned spread3(unsigned v) {
    v = (v | (v << 8)) & 0x00F00Fu;
    v = (v | (v << 4)) & 0x0C30C3u;
    v = (v | (v << 2)) & 0x249249u;
    return v;
}

__device__ __forceinline__ int morton13(const float* __restrict__ dests, int d,
                                        float v0x, float v0y, float v0z,
                                        float isx, float isy, float isz) {
    float gx = (dests[3 * d + 0] - v0x) * isx;
    float gy = (dests[3 * d + 1] - v0y) * isy;
    float gz = (dests[3 * d + 2] - v0z) * isz;
    int ix = min(max((int)gx, 0), VOLD - 1);
    int iy = min(max((int)gy, 0), VOLD - 1);
    int iz = min(max((int)gz, 0), VOLD - 1);
    unsigned m24 = (spread3((unsigned)ix) << 2) |
                   (spread3((unsigned)iy) << 1) |
                    spread3((unsigned)iz);
    return (int)(m24 >> 11);       // top 13 bits -> [0, 8192)
}

__device__ __forceinline__ unsigned samp_fast(const unsigned char* __restrict__ vols,
                                              float ax, float bx, float ay, float by,
                                              float az, float bz, float t) {
    float gx = fmaf(t, bx, ax);
    float gy = fmaf(t, by, ay);
    float gz = fmaf(t, bz, az);
    int ix = (int)gx, iy = (int)gy, iz = (int)gz;  // trunc == floor for g >= 0
    return vols[brick_addr(ix, iy, iz)];
}

__device__ __forceinline__ unsigned samp_chk(const unsigned char* __restrict__ vols,
                                             float ax, float bx, float ay, float by,
                                             float az, float bz, float t) {
    float gx = fmaf(t, bx, ax);
    float gy = fmaf(t, by, ay);
    float gz = fmaf(t, bz, az);
    int ix = (int)gx, iy = (int)gy, iz = (int)gz;
    unsigned v = vols[brick_addr(ix, iy, iz)];   // masked addr => memory-safe
    bool ok = ((unsigned)(ix | iy | iz)) < (unsigned)VOLD;
    return ok ? v : 0u;
}

// ---- fused prep: block 0 = Morton sort of dests; blocks 1.. = u8-brick cvt ----
// cvt thread = one 16B chunk: (lx, brick) with brick z-fastest. Reads 4x float4
// (64 lanes = 64 consecutive bz = contiguous 1KB), writes one aligned int4.

__global__ __launch_bounds__(1024) void prep_kernel(
    const float* __restrict__ in, unsigned char* __restrict__ outv, int n16,
    const float* __restrict__ dests,
    const float* __restrict__ vstart, const float* __restrict__ vspace,
    int n_dst, int* __restrict__ perm) {

    __shared__ int hist[NB];   // 32 KB (sort block only)
    __shared__ int tmp[1024];  // 4 KB

    if (blockIdx.x == 0) {
        int t = threadIdx.x;
        for (int k = t; k < NB; k += 1024) hist[k] = 0;
        __syncthreads();

        float isx = 1.0f / vspace[0], isy = 1.0f / vspace[1], isz = 1.0f / vspace[2];
        float v0x = vstart[0], v0y = vstart[1], v0z = vstart[2];

        // hist pass: register-cache each thread's bucket IDs (static-index unroll)
        int myb[MAXI];
        #pragma unroll
        for (int it = 0; it < MAXI; ++it) {
            int d = t + it * 1024;
            if (d < n_dst) {
                int m = morton13(dests, d, v0x, v0y, v0z, isx, isy, isz);
                myb[it] = m;
                atomicAdd(&hist[m], 1);
            }
        }
        for (int d = t + MAXI * 1024; d < n_dst; d += 1024) {
            int m = morton13(dests, d, v0x, v0y, v0z, isx, isy, isz);
            atomicAdd(&hist[m], 1);
        }
        __syncthreads();

        // exclusive scan over NB buckets (8 per thread)
        const int PER = NB / 1024;  // 8
        int loc[PER];
        int ssum = 0;
        #pragma unroll
        for (int k = 0; k < PER; ++k) { loc[k] = hist[t * PER + k]; ssum += loc[k]; }
        tmp[t] = ssum;
        __syncthreads();
        for (int off = 1; off < 1024; off <<= 1) {
            int v = (t >= off) ? tmp[t - off] : 0;
            __syncthreads();
            tmp[t] += v;
            __syncthreads();
        }
        int run = (t > 0) ? tmp[t - 1] : 0;
        #pragma unroll
        for (int k = 0; k < PER; ++k) { hist[t * PER + k] = run; run += loc[k]; }
        __syncthreads();

        // scatter from registers
        #pragma unroll
        for (int it = 0; it < MAXI; ++it) {
            int d = t + it * 1024;
            if (d < n_dst) {
                int pos = atomicAdd(&hist[myb[it]], 1);
                perm[pos] = d;
            }
        }
        for (int d = t + MAXI * 1024; d < n_dst; d += 1024) {
            int m = morton13(dests, d, v0x, v0y, v0z, isx, isy, isz);
            int pos = atomicAdd(&hist[m], 1);
            perm[pos] = d;
        }
    } else {
        int t = (blockIdx.x - 1) * 1024 + threadIdx.x;
        if (t >= n16) return;
        int lx    = t >> 18;          // 2^18 bricks (256^3 / 64)
        int brick = t & 0x3FFFF;      // bx<<12 | by<<6 | bz  (bz fastest)
        int bx = brick >> 12;
        int by = (brick >> 6) & 63;
        int bz = brick & 63;
        int ix = (bx << 2) + lx;

        union { unsigned char c[16]; int4 i4; } u;
        #pragma unroll
        for (int ly = 0; ly < 4; ++ly) {
            // float4 index: ix*16384 + (by*4+ly)*64 + bz
            float4 a = ((const float4*)in)[(ix << 14) + (((by << 2) + ly) << 6) + bz];
            u.c[(ly << 2) + 0] = (unsigned char)__float2uint_rn(a.x * 255.0f);
            u.c[(ly << 2) + 1] = (unsigned char)__float2uint_rn(a.y * 255.0f);
            u.c[(ly << 2) + 2] = (unsigned char)__float2uint_rn(a.z * 255.0f);
            u.c[(ly << 2) + 3] = (unsigned char)__float2uint_rn(a.w * 255.0f);
        }
        *(int4*)(outv + (brick << 6) + (lx << 4)) = u.i4;
    }
}

// ---- main (u8 brick path) — IDENTICAL to R9/R12/R13 ----------------------

__global__ __launch_bounds__(256) void ct_rpl_u8_kernel(
    const unsigned char* __restrict__ vols,
    const float* __restrict__ sources,
    const float* __restrict__ dests,
    const float* __restrict__ vstart,
    const float* __restrict__ vspace,
    const int* __restrict__ n_samples_p,
    const int* __restrict__ perm,
    int n_src, int n_dst, int G, int nblk,
    float* __restrict__ out) {

    // bijective XCD swizzle
    int b = blockIdx.x;
    int q = nblk >> 3, r = nblk & 7;
    int xcd = b & 7, idx = b >> 3;
    int lb = (xcd < r ? xcd * (q + 1) : r * (q + 1) + (xcd - r) * q) + idx;

    long long ltid = (long long)lb * 256 + threadIdx.x;
    int ray = (int)(ltid >> 3);   // SUBS == 8
    int sub = (int)(ltid & 7);

    // blocked order: ray = (jblk*n_src + s)*G + jloc
    int GS = G * n_src;
    int jblk = ray / GS;
    int rem  = ray - jblk * GS;
    int s    = rem / G;
    int jloc = rem - s * G;
    int j    = jblk * G + jloc;
    if (j >= n_dst || s >= n_src) return;
    int d = perm[j];

    int ns = n_samples_p[0];
    float inv_n = 1.0f / (float)ns;

    float sx = sources[3 * s + 0];
    float sy = sources[3 * s + 1];
    float sz = sources[3 * s + 2];
    float dx = dests[3 * d + 0] - sx;
    float dy = dests[3 * d + 1] - sy;
    float dz = dests[3 * d + 2] - sz;
    float len = sqrtf(dx * dx + dy * dy + dz * dz);

    float v0x = vstart[0], v0y = vstart[1], v0z = vstart[2];
    float ispx = 1.0f / vspace[0], ispy = 1.0f / vspace[1], ispz = 1.0f / vspace[2];

    float ax = (sx - v0x) * ispx, bx = dx * ispx;
    float ay = (sy - v0y) * ispy, by = dy * ispy;
    float az = (sz - v0z) * ispz, bz = dz * ispz;

    // strictly-interior fast path
    float e1x = ax + bx, e1y = ay + by, e1z = az + bz;
    const float MLO = 1e-3f, MHI = (float)VOLD - 1e-3f;
    bool safe = (fminf(ax, e1x) >= MLO) & (fmaxf(ax, e1x) <= MHI) &
                (fminf(ay, e1y) >= MLO) & (fmaxf(ay, e1y) <= MHI) &
                (fminf(az, e1z) >= MLO) & (fmaxf(az, e1z) <= MHI);

    int ilo = 0, ihi = ns - 1;
    if (!safe) {
        float tlo = 0.f, thi = 1.f;
        float aarr[3] = {ax, ay, az};
        float barr[3] = {bx, by, bz};
        #pragma unroll
        for (int axi = 0; axi < 3; ++axi) {
            float a = aarr[axi], bb = barr[axi];
            if (fabsf(bb) > 1e-12f) {
                float r0 = (0.f - a) / bb;
                float r1 = ((float)VOLD - a) / bb;
                tlo = fmaxf(tlo, fminf(r0, r1));
                thi = fminf(thi, fmaxf(r0, r1));
            } else if (a < 0.f || a >= (float)VOLD) {
                thi = -1.f;
            }
        }
        ilo = max(0, (int)ceilf(tlo * (float)ns - 0.5f));
        ihi = min(ns - 1, (int)floorf(thi * (float)ns - 0.5f));
    }

    unsigned acc = 0;
    int i = ilo + sub;
    const float d8 = (float)SUBS * inv_n;

    if (safe) {
        for (; i + 7 * SUBS <= ihi; i += 8 * SUBS) {
            float tb = fmaf((float)i, inv_n, 0.5f * inv_n);
            unsigned s0 = samp_fast(vols, ax, bx, ay, by, az, bz, tb);
            unsigned s1 = samp_fast(vols, ax, bx, ay, by, az, bz, fmaf(1.f, d8, tb));
            unsigned s2 = samp_fast(vols, ax, bx, ay, by, az, bz, fmaf(2.f, d8, tb));
            unsigned s3 = samp_fast(vols, ax, bx, ay, by, az, bz, fmaf(3.f, d8, tb));
            unsigned s4 = samp_fast(vols, ax, bx, ay, by, az, bz, fmaf(4.f, d8, tb));
            unsigned s5 = samp_fast(vols, ax, bx, ay, by, az, bz, fmaf(5.f, d8, tb));
            unsigned s6 = samp_fast(vols, ax, bx, ay, by, az, bz, fmaf(6.f, d8, tb));
            unsigned s7 = samp_fast(vols, ax, bx, ay, by, az, bz, fmaf(7.f, d8, tb));
            acc += ((s0 + s1) + (s2 + s3)) + ((s4 + s5) + (s6 + s7));
        }
        for (; i <= ihi; i += SUBS) {
            float t = fmaf((float)i, inv_n, 0.5f * inv_n);
            acc += samp_fast(vols, ax, bx, ay, by, az, bz, t);
        }
    } else {
        for (; i <= ihi; i += SUBS) {
            float t = fmaf((float)i, inv_n, 0.5f * inv_n);
            acc += samp_chk(vols, ax, bx, ay, by, az, bz, t);
        }
    }

    int ia = (int)acc;
    ia += __shfl_xor(ia, 1);
    ia += __shfl_xor(ia, 2);
    ia += __shfl_xor(ia, 4);

    if (sub == 0) {
        out[s * n_dst + d] = (float)ia * (len * inv_n * (1.0f / 255.0f));
    }
}

// ---- f32 fallback (no workspace / non-256^3) ------------------------------

__global__ __launch_bounds__(256) void ct_rpl_f32_kernel(
    const float* __restrict__ vols,
    const float* __restrict__ sources,
    const float* __restrict__ dests,
    const float* __restrict__ vstart,
    const float* __restrict__ vspace,
    const int* __restrict__ n_samples_p,
    int n_dst, int n_rays,
    float* __restrict__ out) {

    int tid = blockIdx.x * blockDim.x + threadIdx.x;
    int ray = tid >> 3;
    int sub = tid & 7;
    if (ray >= n_rays) return;

    int d = ray % n_dst;
    int s = ray / n_dst;

    int ns = n_samples_p[0];
    float inv_n = 1.0f / (float)ns;

    float sx = sources[3 * s + 0];
    float sy = sources[3 * s + 1];
    float sz = sources[3 * s + 2];
    float dx = dests[3 * d + 0] - sx;
    float dy = dests[3 * d + 1] - sy;
    float dz = dests[3 * d + 2] - sz;
    float len = sqrtf(dx * dx + dy * dy + dz * dz);

    float v0x = vstart[0], v0y = vstart[1], v0z = vstart[2];
    float ispx = 1.0f / vspace[0], ispy = 1.0f / vspace[1], ispz = 1.0f / vspace[2];

    float ax = (sx - v0x) * ispx, bx = dx * ispx;
    float ay = (sy - v0y) * ispy, by = dy * ispy;
    float az = (sz - v0z) * ispz, bz = dz * ispz;

    float acc = 0.0f;
    for (int i = sub; i < ns; i += 8) {
        float t = ((float)i + 0.5f) * inv_n;
        float gx = fmaf(t, bx, ax);
        float gy = fmaf(t, by, ay);
        float gz = fmaf(t, bz, az);
        float fx = floorf(gx), fy = floorf(gy), fz = floorf(gz);
        bool inb = (fx >= 0.f) & (fx < (float)VOLD) &
                   (fy >= 0.f) & (fy < (float)VOLD) &
                   (fz >= 0.f) & (fz < (float)VOLD);
        int ix = (int)fx, iy = (int)fy, iz = (int)fz;
        ix = min(max(ix, 0), VOLD - 1);
        iy = min(max(iy, 0), VOLD - 1);
        iz = min(max(iz, 0), VOLD - 1);
        float v = vols[(ix << 16) | (iy << 8) | iz];
        acc += inb ? v : 0.f;
    }

    acc += __shfl_xor(acc, 1);
    acc += __shfl_xor(acc, 2);
    acc += __shfl_xor(acc, 4);

    if (sub == 0) {
        out[s * n_dst + d] = acc * len * inv_n;
    }
}

extern "C" void kernel_launch(void* const* d_in, const int* in_sizes, int n_in,
                              void* d_out, int out_size, void* d_ws, size_t ws_size,
                              hipStream_t stream) {
    const float* vols    = (const float*)d_in[0];
    const float* sources = (const float*)d_in[1];
    const float* dests   = (const float*)d_in[2];
    const float* vstart  = (const float*)d_in[3];
    const float* vspace  = (const float*)d_in[4];
    const int*   nsamp   = (const int*)d_in[5];

    int nvox  = in_sizes[0];
    int n_src = in_sizes[1] / 3;
    int n_dst = in_sizes[2] / 3;
    int n_rays = n_src * n_dst;

    float* out = (float*)d_out;

    // workspace layout: vol8[nvox] (u8 bricks) | perm[n_dst]
    size_t vol8_bytes = (size_t)nvox;
    size_t sort_bytes = (size_t)n_dst * sizeof(int);
    bool have_ws = (ws_size >= vol8_bytes + sort_bytes) && (nvox == VOLD * VOLD * VOLD);

    if (have_ws) {
        unsigned char* vol8 = (unsigned char*)d_ws;
        int* perm = (int*)((char*)d_ws + vol8_bytes);

        int n16 = nvox / 16;                      // 1,048,576 chunk threads
        int cvt_blocks = (n16 + 1023) / 1024;     // 1024
        hipLaunchKernelGGL(prep_kernel, dim3(cvt_blocks + 1), dim3(1024), 0, stream,
                           vols, vol8, n16, dests, vstart, vspace, n_dst, perm);

        int G = (n_dst + NCHUNK - 1) / NCHUNK;
        long long rays_pad = (long long)NCHUNK * G * n_src;
        long long threads = rays_pad * SUBS;
        int block = 256;
        int nblk = (int)((threads + block - 1) / block);

        hipLaunchKernelGGL(ct_rpl_u8_kernel, dim3(nblk), dim3(block), 0, stream,
                           vol8, sources, dests, vstart, vspace, nsamp,
                           perm, n_src, n_dst, G, nblk, out);
    } else {
        long long threads = (long long)n_rays * 8;
        int block = 256;
        long long grid = (threads + block - 1) / block;
        hipLaunchKernelGGL(ct_rpl_f32_kernel, dim3((unsigned)grid), dim3(block), 0, stream,
                           vols, sources, dests, vstart, vspace, nsamp,
                           n_dst, n_rays, out);
    }
}

// Round 15
// 75.429 us; speedup vs baseline: 1.0318x; 1.0318x over previous
//
#include <hip/hip_runtime.h>
#include <hip/hip_bf16.h>

// CT radiological path length: rpl[s][d] = sum_i vols[nearest(src_s + t_i*(dst_d-src_s))] * len/n
// VOL fixed at 256. Round 15: brick-per-thread cvt — each thread converts one whole 4^3
// brick (=one 64B line): 16 contiguous-1KB-per-wave float4 reads, 4 int4 stores that
// complete the line within one thread (clean write-combining; R14's cross-block partial
// lines reverted). Sort + ray kernel IDENTICAL to R13 best (total 76.4, ray 48.3).

#define VOLD 256
#define NB 8192       // 13-bit Morton prefix buckets
#define SUBS 8        // threads per ray
#define NCHUNK 8      // dest chunks == XCDs
#define MAXI 32       // register-cached dests per sort thread (covers n_dst <= 32768)

__device__ __forceinline__ int brick_addr(int ix, int iy, int iz) {
    return ((ix & 252) << 16) | ((iy & 252) << 10) | ((iz & 252) << 4)
         | ((ix & 3) << 4)   | ((iy & 3) << 2)    | (iz & 3);
}

__device__ __forceinline__ unsigned spread3(unsigned v) {
    v = (v | (v << 8)) & 0x00F00Fu;
    v = (v | (v << 4)) & 0x0C30C3u;
    v = (v | (v << 2)) & 0x249249u;
    return v;
}

__device__ __forceinline__ int morton13(const float* __restrict__ dests, int d,
                                        float v0x, float v0y, float v0z,
                                        float isx, float isy, float isz) {
    float gx = (dests[3 * d + 0] - v0x) * isx;
    float gy = (dests[3 * d + 1] - v0y) * isy;
    float gz = (dests[3 * d + 2] - v0z) * isz;
    int ix = min(max((int)gx, 0), VOLD - 1);
    int iy = min(max((int)gy, 0), VOLD - 1);
    int iz = min(max((int)gz, 0), VOLD - 1);
    unsigned m24 = (spread3((unsigned)ix) << 2) |
                   (spread3((unsigned)iy) << 1) |
                    spread3((unsigned)iz);
    return (int)(m24 >> 11);       // top 13 bits -> [0, 8192)
}

__device__ __forceinline__ unsigned samp_fast(const unsigned char* __restrict__ vols,
                                              float ax, float bx, float ay, float by,
                                              float az, float bz, float t) {
    float gx = fmaf(t, bx, ax);
    float gy = fmaf(t, by, ay);
    float gz = fmaf(t, bz, az);
    int ix = (int)gx, iy = (int)gy, iz = (int)gz;  // trunc == floor for g >= 0
    return vols[brick_addr(ix, iy, iz)];
}

__device__ __forceinline__ unsigned samp_chk(const unsigned char* __restrict__ vols,
                                             float ax, float bx, float ay, float by,
                                             float az, float bz, float t) {
    float gx = fmaf(t, bx, ax);
    float gy = fmaf(t, by, ay);
    float gz = fmaf(t, bz, az);
    int ix = (int)gx, iy = (int)gy, iz = (int)gz;
    unsigned v = vols[brick_addr(ix, iy, iz)];   // masked addr => memory-safe
    bool ok = ((unsigned)(ix | iy | iz)) < (unsigned)VOLD;
    return ok ? v : 0u;
}

// ---- fused prep: block 0 = Morton sort of dests; blocks 1.. = u8-brick cvt ----
// cvt thread = one whole 4^3 brick (64B line). Reads: (lx,ly) x float4-over-lz,
// lanes vary bz => contiguous 1KB per load instr. Writes: 4x int4, line completed
// by this thread alone.

__global__ __launch_bounds__(1024) void prep_kernel(
    const float* __restrict__ in, unsigned char* __restrict__ outv, int nbricks,
    const float* __restrict__ dests,
    const float* __restrict__ vstart, const float* __restrict__ vspace,
    int n_dst, int* __restrict__ perm) {

    __shared__ int hist[NB];   // 32 KB (sort block only)
    __shared__ int tmp[1024];  // 4 KB

    if (blockIdx.x == 0) {
        int t = threadIdx.x;
        for (int k = t; k < NB; k += 1024) hist[k] = 0;
        __syncthreads();

        float isx = 1.0f / vspace[0], isy = 1.0f / vspace[1], isz = 1.0f / vspace[2];
        float v0x = vstart[0], v0y = vstart[1], v0z = vstart[2];

        // hist pass: register-cache each thread's bucket IDs (static-index unroll)
        int myb[MAXI];
        #pragma unroll
        for (int it = 0; it < MAXI; ++it) {
            int d = t + it * 1024;
            if (d < n_dst) {
                int m = morton13(dests, d, v0x, v0y, v0z, isx, isy, isz);
                myb[it] = m;
                atomicAdd(&hist[m], 1);
            }
        }
        for (int d = t + MAXI * 1024; d < n_dst; d += 1024) {
            int m = morton13(dests, d, v0x, v0y, v0z, isx, isy, isz);
            atomicAdd(&hist[m], 1);
        }
        __syncthreads();

        // exclusive scan over NB buckets (8 per thread)
        const int PER = NB / 1024;  // 8
        int loc[PER];
        int ssum = 0;
        #pragma unroll
        for (int k = 0; k < PER; ++k) { loc[k] = hist[t * PER + k]; ssum += loc[k]; }
        tmp[t] = ssum;
        __syncthreads();
        for (int off = 1; off < 1024; off <<= 1) {
            int v = (t >= off) ? tmp[t - off] : 0;
            __syncthreads();
            tmp[t] += v;
            __syncthreads();
        }
        int run = (t > 0) ? tmp[t - 1] : 0;
        #pragma unroll
        for (int k = 0; k < PER; ++k) { hist[t * PER + k] = run; run += loc[k]; }
        __syncthreads();

        // scatter from registers
        #pragma unroll
        for (int it = 0; it < MAXI; ++it) {
            int d = t + it * 1024;
            if (d < n_dst) {
                int pos = atomicAdd(&hist[myb[it]], 1);
                perm[pos] = d;
            }
        }
        for (int d = t + MAXI * 1024; d < n_dst; d += 1024) {
            int m = morton13(dests, d, v0x, v0y, v0z, isx, isy, isz);
            int pos = atomicAdd(&hist[m], 1);
            perm[pos] = d;
        }
    } else {
        int brick = (blockIdx.x - 1) * 1024 + threadIdx.x;
        if (brick >= nbricks) return;
        int bx = brick >> 12;
        int by = (brick >> 6) & 63;
        int bz = brick & 63;
        unsigned char* obase = outv + (brick << 6);
        const float4* inf4 = (const float4*)in;

        #pragma unroll
        for (int lx = 0; lx < 4; ++lx) {
            union { unsigned char c[16]; int4 i4; } u;
            #pragma unroll
            for (int ly = 0; ly < 4; ++ly) {
                // float4 index: ix*16384 + iy*64 + bz ; ix=(bx*4+lx), iy=(by*4+ly)
                float4 a = inf4[(((bx << 2) + lx) << 14) + ((((by << 2) + ly)) << 6) + bz];
                u.c[(ly << 2) + 0] = (unsigned char)__float2uint_rn(a.x * 255.0f);
                u.c[(ly << 2) + 1] = (unsigned char)__float2uint_rn(a.y * 255.0f);
                u.c[(ly << 2) + 2] = (unsigned char)__float2uint_rn(a.z * 255.0f);
                u.c[(ly << 2) + 3] = (unsigned char)__float2uint_rn(a.w * 255.0f);
            }
            *(int4*)(obase + (lx << 4)) = u.i4;
        }
    }
}

// ---- main (u8 brick path) — IDENTICAL to R9/R12/R13 ----------------------

__global__ __launch_bounds__(256) void ct_rpl_u8_kernel(
    const unsigned char* __restrict__ vols,
    const float* __restrict__ sources,
    const float* __restrict__ dests,
    const float* __restrict__ vstart,
    const float* __restrict__ vspace,
    const int* __restrict__ n_samples_p,
    const int* __restrict__ perm,
    int n_src, int n_dst, int G, int nblk,
    float* __restrict__ out) {

    // bijective XCD swizzle
    int b = blockIdx.x;
    int q = nblk >> 3, r = nblk & 7;
    int xcd = b & 7, idx = b >> 3;
    int lb = (xcd < r ? xcd * (q + 1) : r * (q + 1) + (xcd - r) * q) + idx;

    long long ltid = (long long)lb * 256 + threadIdx.x;
    int ray = (int)(ltid >> 3);   // SUBS == 8
    int sub = (int)(ltid & 7);

    // blocked order: ray = (jblk*n_src + s)*G + jloc
    int GS = G * n_src;
    int jblk = ray / GS;
    int rem  = ray - jblk * GS;
    int s    = rem / G;
    int jloc = rem - s * G;
    int j    = jblk * G + jloc;
    if (j >= n_dst || s >= n_src) return;
    int d = perm[j];

    int ns = n_samples_p[0];
    float inv_n = 1.0f / (float)ns;

    float sx = sources[3 * s + 0];
    float sy = sources[3 * s + 1];
    float sz = sources[3 * s + 2];
    float dx = dests[3 * d + 0] - sx;
    float dy = dests[3 * d + 1] - sy;
    float dz = dests[3 * d + 2] - sz;
    float len = sqrtf(dx * dx + dy * dy + dz * dz);

    float v0x = vstart[0], v0y = vstart[1], v0z = vstart[2];
    float ispx = 1.0f / vspace[0], ispy = 1.0f / vspace[1], ispz = 1.0f / vspace[2];

    float ax = (sx - v0x) * ispx, bx = dx * ispx;
    float ay = (sy - v0y) * ispy, by = dy * ispy;
    float az = (sz - v0z) * ispz, bz = dz * ispz;

    // strictly-interior fast path
    float e1x = ax + bx, e1y = ay + by, e1z = az + bz;
    const float MLO = 1e-3f, MHI = (float)VOLD - 1e-3f;
    bool safe = (fminf(ax, e1x) >= MLO) & (fmaxf(ax, e1x) <= MHI) &
                (fminf(ay, e1y) >= MLO) & (fmaxf(ay, e1y) <= MHI) &
                (fminf(az, e1z) >= MLO) & (fmaxf(az, e1z) <= MHI);

    int ilo = 0, ihi = ns - 1;
    if (!safe) {
        float tlo = 0.f, thi = 1.f;
        float aarr[3] = {ax, ay, az};
        float barr[3] = {bx, by, bz};
        #pragma unroll
        for (int axi = 0; axi < 3; ++axi) {
            float a = aarr[axi], bb = barr[axi];
            if (fabsf(bb) > 1e-12f) {
                float r0 = (0.f - a) / bb;
                float r1 = ((float)VOLD - a) / bb;
                tlo = fmaxf(tlo, fminf(r0, r1));
                thi = fminf(thi, fmaxf(r0, r1));
            } else if (a < 0.f || a >= (float)VOLD) {
                thi = -1.f;
            }
        }
        ilo = max(0, (int)ceilf(tlo * (float)ns - 0.5f));
        ihi = min(ns - 1, (int)floorf(thi * (float)ns - 0.5f));
    }

    unsigned acc = 0;
    int i = ilo + sub;
    const float d8 = (float)SUBS * inv_n;

    if (safe) {
        for (; i + 7 * SUBS <= ihi; i += 8 * SUBS) {
            float tb = fmaf((float)i, inv_n, 0.5f * inv_n);
            unsigned s0 = samp_fast(vols, ax, bx, ay, by, az, bz, tb);
            unsigned s1 = samp_fast(vols, ax, bx, ay, by, az, bz, fmaf(1.f, d8, tb));
            unsigned s2 = samp_fast(vols, ax, bx, ay, by, az, bz, fmaf(2.f, d8, tb));
            unsigned s3 = samp_fast(vols, ax, bx, ay, by, az, bz, fmaf(3.f, d8, tb));
            unsigned s4 = samp_fast(vols, ax, bx, ay, by, az, bz, fmaf(4.f, d8, tb));
            unsigned s5 = samp_fast(vols, ax, bx, ay, by, az, bz, fmaf(5.f, d8, tb));
            unsigned s6 = samp_fast(vols, ax, bx, ay, by, az, bz, fmaf(6.f, d8, tb));
            unsigned s7 = samp_fast(vols, ax, bx, ay, by, az, bz, fmaf(7.f, d8, tb));
            acc += ((s0 + s1) + (s2 + s3)) + ((s4 + s5) + (s6 + s7));
        }
        for (; i <= ihi; i += SUBS) {
            float t = fmaf((float)i, inv_n, 0.5f * inv_n);
            acc += samp_fast(vols, ax, bx, ay, by, az, bz, t);
        }
    } else {
        for (; i <= ihi; i += SUBS) {
            float t = fmaf((float)i, inv_n, 0.5f * inv_n);
            acc += samp_chk(vols, ax, bx, ay, by, az, bz, t);
        }
    }

    int ia = (int)acc;
    ia += __shfl_xor(ia, 1);
    ia += __shfl_xor(ia, 2);
    ia += __shfl_xor(ia, 4);

    if (sub == 0) {
        out[s * n_dst + d] = (float)ia * (len * inv_n * (1.0f / 255.0f));
    }
}

// ---- f32 fallback (no workspace / non-256^3) ------------------------------

__global__ __launch_bounds__(256) void ct_rpl_f32_kernel(
    const float* __restrict__ vols,
    const float* __restrict__ sources,
    const float* __restrict__ dests,
    const float* __restrict__ vstart,
    const float* __restrict__ vspace,
    const int* __restrict__ n_samples_p,
    int n_dst, int n_rays,
    float* __restrict__ out) {

    int tid = blockIdx.x * blockDim.x + threadIdx.x;
    int ray = tid >> 3;
    int sub = tid & 7;
    if (ray >= n_rays) return;

    int d = ray % n_dst;
    int s = ray / n_dst;

    int ns = n_samples_p[0];
    float inv_n = 1.0f / (float)ns;

    float sx = sources[3 * s + 0];
    float sy = sources[3 * s + 1];
    float sz = sources[3 * s + 2];
    float dx = dests[3 * d + 0] - sx;
    float dy = dests[3 * d + 1] - sy;
    float dz = dests[3 * d + 2] - sz;
    float len = sqrtf(dx * dx + dy * dy + dz * dz);

    float v0x = vstart[0], v0y = vstart[1], v0z = vstart[2];
    float ispx = 1.0f / vspace[0], ispy = 1.0f / vspace[1], ispz = 1.0f / vspace[2];

    float ax = (sx - v0x) * ispx, bx = dx * ispx;
    float ay = (sy - v0y) * ispy, by = dy * ispy;
    float az = (sz - v0z) * ispz, bz = dz * ispz;

    float acc = 0.0f;
    for (int i = sub; i < ns; i += 8) {
        float t = ((float)i + 0.5f) * inv_n;
        float gx = fmaf(t, bx, ax);
        float gy = fmaf(t, by, ay);
        float gz = fmaf(t, bz, az);
        float fx = floorf(gx), fy = floorf(gy), fz = floorf(gz);
        bool inb = (fx >= 0.f) & (fx < (float)VOLD) &
                   (fy >= 0.f) & (fy < (float)VOLD) &
                   (fz >= 0.f) & (fz < (float)VOLD);
        int ix = (int)fx, iy = (int)fy, iz = (int)fz;
        ix = min(max(ix, 0), VOLD - 1);
        iy = min(max(iy, 0), VOLD - 1);
        iz = min(max(iz, 0), VOLD - 1);
        float v = vols[(ix << 16) | (iy << 8) | iz];
        acc += inb ? v : 0.f;
    }

    acc += __shfl_xor(acc, 1);
    acc += __shfl_xor(acc, 2);
    acc += __shfl_xor(acc, 4);

    if (sub == 0) {
        out[s * n_dst + d] = acc * len * inv_n;
    }
}

extern "C" void kernel_launch(void* const* d_in, const int* in_sizes, int n_in,
                              void* d_out, int out_size, void* d_ws, size_t ws_size,
                              hipStream_t stream) {
    const float* vols    = (const float*)d_in[0];
    const float* sources = (const float*)d_in[1];
    const float* dests   = (const float*)d_in[2];
    const float* vstart  = (const float*)d_in[3];
    const float* vspace  = (const float*)d_in[4];
    const int*   nsamp   = (const int*)d_in[5];

    int nvox  = in_sizes[0];
    int n_src = in_sizes[1] / 3;
    int n_dst = in_sizes[2] / 3;
    int n_rays = n_src * n_dst;

    float* out = (float*)d_out;

    // workspace layout: vol8[nvox] (u8 bricks) | perm[n_dst]
    size_t vol8_bytes = (size_t)nvox;
    size_t sort_bytes = (size_t)n_dst * sizeof(int);
    bool have_ws = (ws_size >= vol8_bytes + sort_bytes) && (nvox == VOLD * VOLD * VOLD);

    if (have_ws) {
        unsigned char* vol8 = (unsigned char*)d_ws;
        int* perm = (int*)((char*)d_ws + vol8_bytes);

        int nbricks = nvox / 64;                  // 262,144 bricks
        int cvt_blocks = (nbricks + 1023) / 1024; // 256
        hipLaunchKernelGGL(prep_kernel, dim3(cvt_blocks + 1), dim3(1024), 0, stream,
                           vols, vol8, nbricks, dests, vstart, vspace, n_dst, perm);

        int G = (n_dst + NCHUNK - 1) / NCHUNK;
        long long rays_pad = (long long)NCHUNK * G * n_src;
        long long threads = rays_pad * SUBS;
        int block = 256;
        int nblk = (int)((threads + block - 1) / block);

        hipLaunchKernelGGL(ct_rpl_u8_kernel, dim3(nblk), dim3(block), 0, stream,
                           vol8, sources, dests, vstart, vspace, nsamp,
                           perm, n_src, n_dst, G, nblk, out);
    } else {
        long long threads = (long long)n_rays * 8;
        int block = 256;
        long long grid = (threads + block - 1) / block;
        hipLaunchKernelGGL(ct_rpl_f32_kernel, dim3((unsigned)grid), dim3(block), 0, stream,
                           vols, sources, dests, vstart, vspace, nsamp,
                           n_dst, n_rays, out);
    }
}